// Round 1
// baseline (58.518 us; speedup 1.0000x reference)
//
#include <hip/hip_runtime.h>
#include <stdint.h>

// Problem constants (from reference setup_inputs)
#define NVARS   128
#define EMBED   256
#define L0      1024
#define NSTEPS  16
#define NBATCH  64
#define LMAX    (L0 + NSTEPS)

typedef unsigned long long u64;

__device__ __forceinline__ u64 shfl_down_u64(u64 x, int off) {
    unsigned lo = (unsigned)(x & 0xffffffffull);
    unsigned hi = (unsigned)(x >> 32);
    lo = __shfl_down(lo, off, 64);
    hi = __shfl_down(hi, off, 64);
    return ((u64)hi << 32) | (u64)lo;
}

// Pack tokens [64][1024][256] fp32 {0,1} -> bitmasks [row][4] u64:
// word0 = dims 0..63 (a lo), word1 = 64..127 (a hi),
// word2 = 128..191 (b lo), word3 = 192..255 (b hi).
__global__ void pack_kernel(const float* __restrict__ tokens, u64* __restrict__ packed) {
    int row = blockIdx.x;          // 0 .. NBATCH*L0-1
    int tid = threadIdx.x;         // 0..255
    float v = tokens[(size_t)row * EMBED + tid];
    u64 m = __ballot(v > 0.5f);    // 64-bit wave ballot; bit k = lane k = dim (wave*64 + k)
    if ((tid & 63) == 0) packed[(size_t)row * 4 + (tid >> 6)] = m;
}

// One block per batch item; 256 threads; 16 sequential autoregressive steps.
// FUSED=1: pack tokens in-kernel (fallback when ws too small).
template <int FUSED>
__launch_bounds__(256)
__global__ void steps_kernel(const float* __restrict__ tokens,
                             const u64* __restrict__ packed,
                             float* __restrict__ out) {
    __shared__ u64 A0[LMAX], A1[LMAX], B0[LMAX], B1[LMAX];
    __shared__ int s_c[4];
    __shared__ u64 s_o0[4], s_o1[4];
    __shared__ u64 s_r0, s_r1;

    const int b   = blockIdx.x;
    const int tid = threadIdx.x;

    if (FUSED) {
        // pack directly from tokens: 8 rows in flight to hide HBM latency
        for (int mb = 0; mb < L0; mb += 8) {
            float v[8];
            #pragma unroll
            for (int r = 0; r < 8; ++r)
                v[r] = tokens[((size_t)(b * L0 + mb + r)) * EMBED + tid];
            #pragma unroll
            for (int r = 0; r < 8; ++r) {
                u64 m = __ballot(v[r] > 0.5f);
                if ((tid & 63) == 0) {
                    int w = tid >> 6, row = mb + r;
                    if      (w == 0) A0[row] = m;
                    else if (w == 1) A1[row] = m;
                    else if (w == 2) B0[row] = m;
                    else             B1[row] = m;
                }
            }
        }
    } else {
        const u64* p = packed + (size_t)b * L0 * 4;
        for (int i = tid; i < L0; i += 256) {
            A0[i] = p[i * 4 + 0];
            A1[i] = p[i * 4 + 1];
            B0[i] = p[i * 4 + 2];
            B1[i] = p[i * 4 + 3];
        }
    }
    __syncthreads();

    const float TP = 0.46211715726f;   // tanh(0.5)
    int L = L0;

    for (int step = 0; step < NSTEPS; ++step) {
        const u64 qb0 = B0[L - 1], qb1 = B1[L - 1];   // LDS broadcast

        // per-thread scan: min count + OR of b-bits over argmin rows
        int cmin = 0x7fffffff;
        u64 o0 = 0, o1 = 0;
        for (int i = tid; i < L; i += 256) {
            int c = __popcll(A0[i] & ~qb0) + __popcll(A1[i] & ~qb1);
            if (c < cmin)       { cmin = c; o0 = B0[i]; o1 = B1[i]; }
            else if (c == cmin) { o0 |= B0[i]; o1 |= B1[i]; }
        }

        // 64-lane wave reduction
        #pragma unroll
        for (int off = 32; off > 0; off >>= 1) {
            int c2 = __shfl_down(cmin, off, 64);
            u64 p0 = shfl_down_u64(o0, off);
            u64 p1 = shfl_down_u64(o1, off);
            if (c2 < cmin)       { cmin = c2; o0 = p0; o1 = p1; }
            else if (c2 == cmin) { o0 |= p0; o1 |= p1; }
        }
        if ((tid & 63) == 0) {
            int w = tid >> 6;
            s_c[w] = cmin; s_o0[w] = o0; s_o1[w] = o1;
        }
        __syncthreads();

        if (tid == 0) {
            int rc = s_c[0]; u64 r0 = s_o0[0], r1 = s_o1[0];
            #pragma unroll
            for (int w = 1; w < 4; ++w) {
                if (s_c[w] < rc)       { rc = s_c[w]; r0 = s_o0[w]; r1 = s_o1[w]; }
                else if (s_c[w] == rc) { r0 |= s_o0[w]; r1 |= s_o1[w]; }
            }
            s_r0 = r0; s_r1 = r1;
            // append next token: a = 0, b = succ = or | qb
            A0[L] = 0; A1[L] = 0;
            B0[L] = r0 | qb0; B1[L] = r1 | qb1;
        }
        __syncthreads();

        if (tid < NVARS) {
            u64 ow = (tid < 64) ? s_r0 : s_r1;
            u64 qw = (tid < 64) ? qb0  : qb1;
            int bit = tid & 63;
            float v = ((ow >> bit) & 1) ? 1.0f
                                        : (((qw >> bit) & 1) ? TP : -TP);
            out[((size_t)b * NSTEPS + step) * NVARS + tid] = v;
        }
        ++L;
        __syncthreads();   // protect s_c/s_o reuse + appended row visibility
    }
}

extern "C" void kernel_launch(void* const* d_in, const int* in_sizes, int n_in,
                              void* d_out, int out_size, void* d_ws, size_t ws_size,
                              hipStream_t stream) {
    const float* tokens = (const float*)d_in[0];
    float* out = (float*)d_out;

    const size_t need = (size_t)NBATCH * L0 * 4 * sizeof(u64);   // 2 MiB
    if (ws_size >= need) {
        u64* packed = (u64*)d_ws;
        pack_kernel<<<NBATCH * L0, 256, 0, stream>>>(tokens, packed);
        steps_kernel<0><<<NBATCH, 256, 0, stream>>>(tokens, packed, out);
    } else {
        steps_kernel<1><<<NBATCH, 256, 0, stream>>>(tokens, nullptr, out);
    }
}

// Round 2
// 28.625 us; speedup vs baseline: 2.0443x; 2.0443x over previous
//
#include <hip/hip_runtime.h>
#include <stdint.h>

// Problem constants (from reference setup_inputs)
#define NVARS   128
#define EMBED   256
#define L0      1024
#define NSTEPS  16
#define NBATCH  64
#define NROWS   (NBATCH * L0)

typedef unsigned long long u64;
typedef unsigned int u32;

__device__ __forceinline__ u64 shfl_down_u64(u64 x, int off) {
    u32 lo = (u32)x, hi = (u32)(x >> 32);
    lo = __shfl_down(lo, off, 64);
    hi = __shfl_down(hi, off, 64);
    return ((u64)hi << 32) | (u64)lo;
}

// Pack tokens [64*1024 rows][256 fp32 {0,1}] -> 4 u64 words per row.
// Wave per row: lane l loads float4 (dims 4l..4l+3), 4 ballots m0..m3.
// Permuted layout (popcount/OR are permutation-invariant; output remaps):
//   word0 (A0) = lo32(m0) | lo32(m1)<<32     (a-half = lanes 0..31)
//   word1 (A1) = lo32(m2) | lo32(m3)<<32
//   word2 (B0) = hi32(m0) | hi32(m1)<<32     (b-half = lanes 32..63)
//   word3 (B1) = hi32(m2) | hi32(m3)<<32
// var v (0..127): word = 2 + ((v>>1)&1), bit = (v>>2) | ((v&1)<<5)
__global__ __launch_bounds__(256) void pack_kernel(const float4* __restrict__ tok4,
                                                   u64* __restrict__ packed) {
    const int lane = threadIdx.x & 63;
    const int gw   = (blockIdx.x * 256 + threadIdx.x) >> 6;   // 0..8191
    #pragma unroll
    for (int it = 0; it < 8; ++it) {
        const int row = gw + it * 8192;                        // 8192 waves * 8 = 65536
        float4 v = tok4[(size_t)row * 64 + lane];
        u64 m0 = __ballot(v.x > 0.5f);
        u64 m1 = __ballot(v.y > 0.5f);
        u64 m2 = __ballot(v.z > 0.5f);
        u64 m3 = __ballot(v.w > 0.5f);
        u64 w;
        if      (lane == 0) w = (m0 & 0xffffffffull) | (m1 << 32);
        else if (lane == 1) w = (m2 & 0xffffffffull) | (m3 << 32);
        else if (lane == 2) w = (m0 >> 32) | (m1 & 0xffffffff00000000ull);
        else                w = (m2 >> 32) | (m3 & 0xffffffff00000000ull);
        if (lane < 4) packed[(size_t)row * 4 + lane] = w;
    }
}

// One block per batch item; 256 threads; rows register-resident (4 rows/thread).
// Step 0: full min+argmin-OR reduction.
// Steps 1..15: cmin==0 guaranteed (query row has a==0); r_s = qb_s | OR{base rows
// with cnt==0}; counts updated incrementally by popcount(a & delta_qb); appended
// rows' b-masks are subsets of qb (monotone) so they never need materializing.
__global__ __launch_bounds__(256) void steps_kernel(const u64* __restrict__ packed,
                                                    float* __restrict__ out) {
    __shared__ int s_c[4];
    __shared__ u64 s_o0[4], s_o1[4];
    __shared__ u64 s_rp0, s_rp1;     // pure r_0 (step 0 needs 3-way output)
    __shared__ u32 s_acc[4];         // running union U: qb_s, grows to r_s
    __shared__ u64 s_qb0s, s_qb1s;

    const int bb = blockIdx.x, tid = threadIdx.x;
    const int lane = tid & 63, w = tid >> 6;

    // load own 4 rows (32 B/thread, 2 KB contiguous per wave)
    u64 ra0[4], ra1[4], rb0[4], rb1[4];
    const u64* p = packed + (size_t)bb * L0 * 4;
    #pragma unroll
    for (int i = 0; i < 4; ++i) {
        const u64* q = p + (size_t)(i * 256 + tid) * 4;
        ra0[i] = q[0]; ra1[i] = q[1]; rb0[i] = q[2]; rb1[i] = q[3];
    }
    if (tid == 255) { s_qb0s = rb0[3]; s_qb1s = rb1[3]; }   // row 1023 = query_0
    __syncthreads();
    const u64 qb0 = s_qb0s, qb1 = s_qb1s;

    // ---- step 0: full argmin reduction ----
    int c[4];
    int cm = 0x7fffffff; u64 o0 = 0, o1 = 0;
    #pragma unroll
    for (int i = 0; i < 4; ++i) {
        c[i] = __popcll(ra0[i] & ~qb0) + __popcll(ra1[i] & ~qb1);
        if (c[i] < cm)       { cm = c[i]; o0 = rb0[i]; o1 = rb1[i]; }
        else if (c[i] == cm) { o0 |= rb0[i]; o1 |= rb1[i]; }
    }
    #pragma unroll
    for (int off = 32; off; off >>= 1) {
        int c2 = __shfl_down(cm, off, 64);
        u64 p0 = shfl_down_u64(o0, off), p1 = shfl_down_u64(o1, off);
        if (c2 < cm)       { cm = c2; o0 = p0; o1 = p1; }
        else if (c2 == cm) { o0 |= p0; o1 |= p1; }
    }
    if (lane == 0) { s_c[w] = cm; s_o0[w] = o0; s_o1[w] = o1; }
    __syncthreads();
    if (tid == 0) {
        int rc = s_c[0]; u64 r0 = s_o0[0], r1 = s_o1[0];
        #pragma unroll
        for (int k = 1; k < 4; ++k) {
            if (s_c[k] < rc)       { rc = s_c[k]; r0 = s_o0[k]; r1 = s_o1[k]; }
            else if (s_c[k] == rc) { r0 |= s_o0[k]; r1 |= s_o1[k]; }
        }
        s_rp0 = r0; s_rp1 = r1;
        u64 u0 = r0 | qb0, u1 = r1 | qb1;   // qb_1
        s_acc[0] = (u32)u0; s_acc[1] = (u32)(u0 >> 32);
        s_acc[2] = (u32)u1; s_acc[3] = (u32)(u1 >> 32);
    }
    __syncthreads();

    const float TP = 0.46211715726000974f;   // tanh(0.5)
    float* ob = out + (size_t)bb * NSTEPS * NVARS;
    if (tid < NVARS) {
        const int wi = (tid >> 1) & 1, bit = (tid >> 2) | ((tid & 1) << 5);
        u64 rw = wi ? s_rp1 : s_rp0;
        u64 qw = wi ? qb1 : qb0;
        ob[tid] = ((rw >> bit) & 1) ? 1.0f : (((qw >> bit) & 1) ? TP : -TP);
    }
    u64 rcur0 = (u64)s_acc[0] | ((u64)s_acc[1] << 32);   // qb_1
    u64 rcur1 = (u64)s_acc[2] | ((u64)s_acc[3] << 32);
    u64 qbp0 = qb0, qbp1 = qb1;
    __syncthreads();   // all reads of s_rp/s_acc done before step-1 atomics

    // ---- steps 1..15: incremental fast path ----
    for (int s = 1; s < NSTEPS; ++s) {
        const u64 d0 = rcur0 & ~qbp0, d1 = rcur1 & ~qbp1;   // qb delta
        if (d0 | d1) {
            #pragma unroll
            for (int i = 0; i < 4; ++i)
                c[i] -= __popcll(ra0[i] & d0) + __popcll(ra1[i] & d1);
            qbp0 = rcur0; qbp1 = rcur1;
        }
        #pragma unroll
        for (int i = 0; i < 4; ++i) {
            if (c[i] == 0) {   // argmin base row: contribute new b-bits
                u64 nb0 = rb0[i] & ~rcur0, nb1 = rb1[i] & ~rcur1;
                if (nb0 | nb1) {
                    if ((u32)nb0)         atomicOr(&s_acc[0], (u32)nb0);
                    if ((u32)(nb0 >> 32)) atomicOr(&s_acc[1], (u32)(nb0 >> 32));
                    if ((u32)nb1)         atomicOr(&s_acc[2], (u32)nb1);
                    if ((u32)(nb1 >> 32)) atomicOr(&s_acc[3], (u32)(nb1 >> 32));
                }
            }
        }
        __syncthreads();   // atomics complete
        const u64 rn0 = (u64)s_acc[0] | ((u64)s_acc[1] << 32);   // r_s
        const u64 rn1 = (u64)s_acc[2] | ((u64)s_acc[3] << 32);
        if (tid < NVARS) {
            const int wi = (tid >> 1) & 1, bit = (tid >> 2) | ((tid & 1) << 5);
            u64 rw = wi ? rn1 : rn0;
            // r_s >= qb_s, so qb bit set => r bit set => 1.0; else qb bit is 0 => -TP
            ob[s * NVARS + tid] = ((rw >> bit) & 1) ? 1.0f : -TP;
        }
        rcur0 = rn0; rcur1 = rn1;
        __syncthreads();   // reads done before next step's atomics
    }
}

extern "C" void kernel_launch(void* const* d_in, const int* in_sizes, int n_in,
                              void* d_out, int out_size, void* d_ws, size_t ws_size,
                              hipStream_t stream) {
    const float4* tok4 = (const float4*)d_in[0];
    float* out = (float*)d_out;
    u64* packed = (u64*)d_ws;   // needs 2 MiB; ws observed at 256 MiB

    pack_kernel<<<2048, 256, 0, stream>>>(tok4, packed);
    steps_kernel<<<NBATCH, 256, 0, stream>>>(packed, out);
}